// Round 11
// baseline (8052.339 us; speedup 1.0000x reference)
//
#include <hip/hip_runtime.h>
#include <hip/hip_bf16.h>

#define T_TOTAL 1024
#define BATCH   64
#define HID     512
#define NSCAN   256   // scan blocks per fused dispatch

__device__ __forceinline__ float fast_sigmoid(float x) {
    return 1.f / (1.f + __expf(-x));
}
__device__ __forceinline__ float fast_tanh(float x) {
    float ax = fabsf(x);
    float e  = __expf(-2.f * ax);
    float t  = (1.f - e) / (1.f + e);
    return copysignf(t, x);
}

// ---------------------------------------------------------------------------
// Standalone GEMM (for the first xg chunk and the final FC):
// C[m,n] = sum_k A[rowg(m),k] * W[n,k] + bias[n]
// ---------------------------------------------------------------------------
template<int BM, int BN, int TM, int TN>
__global__ __launch_bounds__(256, 2)
void gemm_bt_k(const float* __restrict__ A, const float* __restrict__ W,
               const float* __restrict__ bias, float* __restrict__ C,
               int K, int T, int Tc, int t0, int N)
{
    constexpr int BK = 16;
    constexpr int WSTR = BN + (BN / 32) * 4;
    static_assert(BM / TM == 16 && BN / TN == 16, "256 threads required");
    __shared__ float As[BK][BM + 4];
    __shared__ float Ws[BK][WSTR];

    const int tid = threadIdx.x;
    const int tx  = tid & 15;
    const int ty  = tid >> 4;
    const int m0  = blockIdx.y * BM;
    const int n0  = blockIdx.x * BN;
    const int nA  = tx * TN;
    const int nsw = nA + ((nA >> 5) << 2);

    float acc[TM][TN];
#pragma unroll
    for (int i = 0; i < TM; ++i)
#pragma unroll
        for (int j = 0; j < TN; ++j) acc[i][j] = 0.f;

    for (int k0 = 0; k0 < K; k0 += BK) {
#pragma unroll
        for (int i = 0; i < (BM * BK) / 1024; ++i) {
            int id = tid + (i << 8);
            int m  = id >> 2;
            int kq = (id & 3) << 2;
            int mloc = m0 + m;
            int rowg = (mloc / Tc) * T + t0 + (mloc % Tc);
            const float4 v = *reinterpret_cast<const float4*>(A + (size_t)rowg * K + k0 + kq);
            As[kq + 0][m] = v.x; As[kq + 1][m] = v.y;
            As[kq + 2][m] = v.z; As[kq + 3][m] = v.w;
        }
#pragma unroll
        for (int i = 0; i < (BN * BK) / 1024; ++i) {
            int id = tid + (i << 8);
            int n  = id >> 2;
            int kq = (id & 3) << 2;
            const float4 v = *reinterpret_cast<const float4*>(W + (size_t)(n0 + n) * K + k0 + kq);
            int np = n + ((n >> 5) << 2);
            Ws[kq + 0][np] = v.x; Ws[kq + 1][np] = v.y;
            Ws[kq + 2][np] = v.z; Ws[kq + 3][np] = v.w;
        }
        __syncthreads();
#pragma unroll
        for (int k = 0; k < BK; ++k) {
            float a[TM], b[TN];
#pragma unroll
            for (int i = 0; i < TM; i += 4)
                *reinterpret_cast<float4*>(&a[i]) =
                    *reinterpret_cast<const float4*>(&As[k][ty * TM + i]);
#pragma unroll
            for (int j = 0; j < TN; j += 4)
                *reinterpret_cast<float4*>(&b[j]) =
                    *reinterpret_cast<const float4*>(&Ws[k][nsw + j]);
#pragma unroll
            for (int i = 0; i < TM; ++i)
#pragma unroll
                for (int j = 0; j < TN; ++j)
                    acc[i][j] = fmaf(a[i], b[j], acc[i][j]);
        }
        __syncthreads();
    }
#pragma unroll
    for (int i = 0; i < TM; ++i) {
        const size_t crow = (size_t)(m0 + ty * TM + i) * N + n0 + nA;
#pragma unroll
        for (int j = 0; j < TN; j += 4) {
            float4 bv = *reinterpret_cast<const float4*>(bias + n0 + nA + j);
            float4 v;
            v.x = acc[i][j + 0] + bv.x; v.y = acc[i][j + 1] + bv.y;
            v.z = acc[i][j + 2] + bv.z; v.w = acc[i][j + 3] + bv.w;
            *reinterpret_cast<float4*>(C + crow + j) = v;
        }
    }
}

// ---------------------------------------------------------------------------
// Fused dispatch: blocks [0,256) = R10 scan (unchanged math, s_setprio(2));
// blocks [256, 256+gNB) = GEMM workers computing the NEXT chunk's xg
// (layer-0 xg depends only on x; layer-1 xg chunk c reads y0 chunk c,
// completed a previous dispatch -> dispatch-boundary visibility, no new
// cross-block protocol, no deadlock: workers never wait on scans).
// Workers soak up the ~38% issue slots the scan leaves idle (poll sleep,
// barrier, lgkm waits); scan waves at priority 2 keep their critical path.
// ---------------------------------------------------------------------------
struct ScanSmem {
    float h_lds[2][1024];
    float part[2][8 * 392];
};
struct GemmSmem {
    float As[16][132];
    float Ws[16][144];
};
union FusedSmem { ScanSmem s; GemmSmem g; };

__global__ __launch_bounds__(512, 2)
void scan_gemm_fused(const float* __restrict__ xg,    // chunk-local [64][Tc][1536]
                     const float* __restrict__ w_hh,  // [1536][512]
                     const float* __restrict__ b_hh,  // [1536]
                     float* __restrict__ y,           // [64][1024][512]
                     unsigned long long* __restrict__ hbuf, // [32][2][2][512]
                     int t0, int Tc, int tagbase,
                     const float* __restrict__ gA,    // worker A (x or y)
                     const float* __restrict__ gW,    // worker w_ih [1536][gK]
                     const float* __restrict__ gbias, // worker b_ih
                     float* __restrict__ gC,          // worker xg out (other buf)
                     int gK, int gt0, int gNB)
{
    __shared__ FusedSmem sm;
    const int tid = threadIdx.x;

    if (blockIdx.x < NSCAN) {
        // ================= SCAN ROLE (R10, validated) =================
        __builtin_amdgcn_s_setprio(2);
        const int grp = blockIdx.x & 31;
        const int os  = blockIdx.x >> 5;
        const int D0  = os << 6;
        const int d   = tid & 63;
        const int kc  = tid >> 6;
        const int bg  = grp << 1;

        float4 w4[3][16];
#pragma unroll
        for (int g = 0; g < 3; ++g) {
            const float* wr = w_hh + (size_t)(g * 512 + D0 + d) * 512 + kc * 64;
#pragma unroll
            for (int j = 0; j < 16; ++j)
                w4[g][j] = *reinterpret_cast<const float4*>(wr + (j << 2));
        }
        float bias_r = 0.f, bias_z = 0.f, bias_n = 0.f;
        if (tid < 128) {
            bias_r = b_hh[       D0 + d];
            bias_z = b_hh[ 512 + D0 + d];
            bias_n = b_hh[1024 + D0 + d];
        }
        const int b_loc = tid >> 6;

        for (int tl = 0; tl < Tc; ++tl) {
            const int tg = t0 + tl;
            float* hl = sm.s.h_lds[tl & 1];
            float* pt = sm.s.part[tl & 1];

            float xr = 0.f, xz = 0.f, xn = 0.f;
            if (tid < 128) {
                const size_t rowo = ((size_t)(bg + b_loc) * Tc + tl) * 1536 + D0 + d;
                xr = xg[rowo];
                xz = xg[rowo + 512];
                xn = xg[rowo + 1024];
            }

            if (tg == 0) {
                hl[      kc * 64 + d] = 0.f;
                hl[512 + kc * 64 + d] = 0.f;
            } else {
                const unsigned long long* hsrc =
                    hbuf + (size_t)(grp * 2 + ((tg - 1) & 1)) * 1024 + kc * 64;
                const unsigned int tagexp = (unsigned int)(tagbase + tl - 1);
                unsigned long long v0 = 0, v1 = 0;
                unsigned int pend = 0x3u;
                while (pend) {
                    if (pend & 1u)
                        v0 = __hip_atomic_load(hsrc + d,
                                __ATOMIC_RELAXED, __HIP_MEMORY_SCOPE_AGENT);
                    if (pend & 2u)
                        v1 = __hip_atomic_load(hsrc + 512 + d,
                                __ATOMIC_RELAXED, __HIP_MEMORY_SCOPE_AGENT);
                    if ((pend & 1u) && (unsigned int)(v0 >> 32) == tagexp) {
                        union { unsigned int u; float f; } cv; cv.u = (unsigned int)v0;
                        hl[kc * 64 + d] = cv.f;
                        pend &= ~1u;
                    }
                    if ((pend & 2u) && (unsigned int)(v1 >> 32) == tagexp) {
                        union { unsigned int u; float f; } cv; cv.u = (unsigned int)v1;
                        hl[512 + kc * 64 + d] = cv.f;
                        pend &= ~2u;
                    }
                    if (pend) __builtin_amdgcn_s_sleep(1);
                }
            }
            __builtin_amdgcn_s_waitcnt(0xC07F);   // lgkmcnt(0)

            float acc[3][2];
#pragma unroll
            for (int g = 0; g < 3; ++g) { acc[g][0] = 0.f; acc[g][1] = 0.f; }
            const float* hb = hl + kc * 64;
#pragma unroll
            for (int j = 0; j < 16; ++j) {
                const float4 h0 = *reinterpret_cast<const float4*>(hb + (j << 2));
                const float4 h1 = *reinterpret_cast<const float4*>(hb + 512 + (j << 2));
#pragma unroll
                for (int g = 0; g < 3; ++g) {
                    const float4 wv = w4[g][j];
                    acc[g][0] = fmaf(wv.x, h0.x, acc[g][0]);
                    acc[g][0] = fmaf(wv.y, h0.y, acc[g][0]);
                    acc[g][0] = fmaf(wv.z, h0.z, acc[g][0]);
                    acc[g][0] = fmaf(wv.w, h0.w, acc[g][0]);
                    acc[g][1] = fmaf(wv.x, h1.x, acc[g][1]);
                    acc[g][1] = fmaf(wv.y, h1.y, acc[g][1]);
                    acc[g][1] = fmaf(wv.z, h1.z, acc[g][1]);
                    acc[g][1] = fmaf(wv.w, h1.w, acc[g][1]);
                }
            }
            {
                float* pp = pt + kc * 392 + d;
#pragma unroll
                for (int g = 0; g < 3; ++g) {
                    pp[g * 128]      = acc[g][0];
                    pp[g * 128 + 64] = acc[g][1];
                }
            }
            __syncthreads();

            if (tid < 128) {
                float sr = bias_r, sz = bias_z, sn = bias_n;
#pragma unroll
                for (int q = 0; q < 8; ++q) {
                    sr += pt[q * 392 +       tid];
                    sz += pt[q * 392 + 128 + tid];
                    sn += pt[q * 392 + 256 + tid];
                }
                const int D = D0 + d;
                const float hp = hl[b_loc * 512 + D];
                const float r  = fast_sigmoid(xr + sr);
                const float z  = fast_sigmoid(xz + sz);
                const float nv = fast_tanh(xn + r * sn);
                const float h  = (1.f - z) * nv + z * hp;
                union { float f; unsigned int u; } cv; cv.f = h;
                const unsigned long long pk =
                    ((unsigned long long)(unsigned int)(tagbase + tl) << 32) | cv.u;
                unsigned long long* hdst =
                    hbuf + (size_t)(grp * 2 + (tg & 1)) * 1024 + b_loc * 512 + D;
                __hip_atomic_store(hdst, pk, __ATOMIC_RELAXED,
                                   __HIP_MEMORY_SCOPE_AGENT);
                y[((size_t)(bg + b_loc) * T_TOTAL + tg) * HID + D] = h;
            }
        }
    } else {
        // ================= GEMM WORKER ROLE =================
        const int bid = blockIdx.x - NSCAN;
        if (bid >= gNB) return;
        const int NXT = 12;                    // 1536/128 n-tiles
        const int by  = bid / NXT;
        const int bx  = bid - by * NXT;
        const int m0  = by << 7;
        const int n0  = bx << 7;
        const int tx  = tid & 31;
        const int ty  = tid >> 5;
        const int nA  = tx << 2;
        const int nsw = nA + ((nA >> 5) << 2);

        const int mA   = tid >> 2;             // local m row this thread stages
        const int kqA  = (tid & 3) << 2;
        const int mloc = m0 + mA;
        const int rowg = (mloc / Tc) * T_TOTAL + gt0 + (mloc % Tc);

        float acc[8][4];
#pragma unroll
        for (int i = 0; i < 8; ++i)
#pragma unroll
            for (int j = 0; j < 4; ++j) acc[i][j] = 0.f;

        for (int k0 = 0; k0 < gK; k0 += 16) {
            {
                const float4 v = *reinterpret_cast<const float4*>(
                    gA + (size_t)rowg * gK + k0 + kqA);
                sm.g.As[kqA + 0][mA] = v.x; sm.g.As[kqA + 1][mA] = v.y;
                sm.g.As[kqA + 2][mA] = v.z; sm.g.As[kqA + 3][mA] = v.w;
            }
            {
                const float4 v = *reinterpret_cast<const float4*>(
                    gW + (size_t)(n0 + mA) * gK + k0 + kqA);
                int np = mA + ((mA >> 5) << 2);
                sm.g.Ws[kqA + 0][np] = v.x; sm.g.Ws[kqA + 1][np] = v.y;
                sm.g.Ws[kqA + 2][np] = v.z; sm.g.Ws[kqA + 3][np] = v.w;
            }
            __syncthreads();
#pragma unroll
            for (int k = 0; k < 16; ++k) {
                float a[8], b[4];
                *reinterpret_cast<float4*>(&a[0]) =
                    *reinterpret_cast<const float4*>(&sm.g.As[k][ty * 8]);
                *reinterpret_cast<float4*>(&a[4]) =
                    *reinterpret_cast<const float4*>(&sm.g.As[k][ty * 8 + 4]);
                *reinterpret_cast<float4*>(&b[0]) =
                    *reinterpret_cast<const float4*>(&sm.g.Ws[k][nsw]);
#pragma unroll
                for (int i = 0; i < 8; ++i)
#pragma unroll
                    for (int j = 0; j < 4; ++j)
                        acc[i][j] = fmaf(a[i], b[j], acc[i][j]);
            }
            __syncthreads();
        }
        const float4 bv = *reinterpret_cast<const float4*>(gbias + n0 + nA);
#pragma unroll
        for (int i = 0; i < 8; ++i) {
            float4 v;
            v.x = acc[i][0] + bv.x; v.y = acc[i][1] + bv.y;
            v.z = acc[i][2] + bv.z; v.w = acc[i][3] + bv.w;
            *reinterpret_cast<float4*>(
                gC + (size_t)(m0 + ty * 8 + i) * 1536 + n0 + nA) = v;
        }
    }
}

// ---------------------------------------------------------------------------
extern "C" void kernel_launch(void* const* d_in, const int* in_sizes, int n_in,
                              void* d_out, int out_size, void* d_ws, size_t ws_size,
                              hipStream_t stream)
{
    const float* x       = (const float*)d_in[0];
    const float* w_ih[2] = {(const float*)d_in[1], (const float*)d_in[5]};
    const float* w_hh[2] = {(const float*)d_in[2], (const float*)d_in[6]};
    const float* b_ih[2] = {(const float*)d_in[3], (const float*)d_in[7]};
    const float* b_hh[2] = {(const float*)d_in[4], (const float*)d_in[8]};
    const float* fc_w    = (const float*)d_in[9];
    const float* fc_b    = (const float*)d_in[10];
    float* out = (float*)d_out;

    const size_t Y_BYTES = (size_t)BATCH * T_TOTAL * HID * 4;   // 128 MiB
    const size_t H_BYTES = (size_t)32 * 2 * 2 * 512 * 8;        // 512 KiB
    int Tc = 256;
    while (Tc > 32) {
        size_t need = 2 * ((size_t)BATCH * Tc * 1536 * 4) + Y_BYTES + H_BYTES;
        if (need <= ws_size) break;
        Tc >>= 1;
    }
    const size_t XG_BYTES = (size_t)BATCH * Tc * 1536 * 4;

    char* p = (char*)d_ws;
    float* xgb[2];
    xgb[0] = (float*)p;                        p += XG_BYTES;
    xgb[1] = (float*)p;                        p += XG_BYTES;
    float* y_buf = (float*)p;                  p += Y_BYTES;
    unsigned long long* hbuf = (unsigned long long*)p;

    const int nch = T_TOTAL / Tc;
    const int nsteps = 2 * nch;
    const int WNB = ((BATCH * Tc) / 128) * 12;   // worker blocks per GEMM

    // first xg chunk (layer 0, chunk 0) standalone
    {
        dim3 g1(12, (BATCH * Tc) / 128);
        gemm_bt_k<128, 128, 8, 8><<<g1, 256, 0, stream>>>(
            x, w_ih[0], b_ih[0], xgb[0], 64, T_TOTAL, Tc, 0, 1536);
    }

    for (int i = 0; i < nsteps; ++i) {
        const int L = i / nch, c = i % nch;
        const bool has_next = (i + 1 < nsteps);
        const int L2 = (i + 1) / nch, c2 = (i + 1) % nch;
        const int gNB = has_next ? WNB : 0;
        dim3 grid(NSCAN + gNB);
        scan_gemm_fused<<<grid, 512, 0, stream>>>(
            xgb[i & 1], w_hh[L], b_hh[L], y_buf, hbuf,
            c * Tc, Tc, (L << 11) + c * Tc,
            has_next ? (L2 ? y_buf : x) : nullptr,
            has_next ? w_ih[L2] : nullptr,
            has_next ? b_ih[L2] : nullptr,
            has_next ? xgb[(i + 1) & 1] : nullptr,
            L2 ? 512 : 64, c2 * Tc, gNB);
    }

    // final FC
    dim3 g2(1, (BATCH * T_TOTAL) / 128);
    gemm_bt_k<128, 64, 8, 4><<<g2, 256, 0, stream>>>(
        y_buf, fc_w, fc_b, out, HID, BATCH * T_TOTAL, BATCH * T_TOTAL, 0, 64);
}